// Round 7
// baseline (586.999 us; speedup 1.0000x reference)
//
#include <hip/hip_runtime.h>
#include <hip/hip_bf16.h>

#define NN 100000
#define NE 1000000
#define DD 128
#define RR 8
#define KCAT 1152              // 9*128 (8 relations + root)
#define NBLK 6250              // NN/16 exactly

typedef short bf16x8 __attribute__((ext_vector_type(8)));
typedef float f32x4 __attribute__((ext_vector_type(4)));

__device__ __forceinline__ unsigned short f2bf(float f) {
    union { float f; unsigned int u; } c; c.f = f;
    unsigned int u = c.u;
    u += 0x7fffu + ((u >> 16) & 1u);   // round-to-nearest-even
    return (unsigned short)(u >> 16);
}

// fp32 -> bf16, 4 elems/thread
__global__ __launch_bounds__(256) void cvt_x_k(const float* __restrict__ in,
                                               unsigned short* __restrict__ out,
                                               int n4) {
    int i = blockIdx.x * 256 + threadIdx.x;
    if (i >= n4) return;
    float4 v = reinterpret_cast<const float4*>(in)[i];
    ushort4 o;
    o.x = f2bf(v.x); o.y = f2bf(v.y); o.z = f2bf(v.z); o.w = f2bf(v.w);
    reinterpret_cast<ushort4*>(out)[i] = o;
}

// Build Wcat[e][m*128+d] = W[m][d][e] (m<8) / root[d][e] (m==8), bf16, both layers.
__global__ __launch_bounds__(256) void cvt_w_k(const float* __restrict__ W1,
                                               const float* __restrict__ r1,
                                               const float* __restrict__ W2,
                                               const float* __restrict__ r2,
                                               unsigned short* __restrict__ wc1,
                                               unsigned short* __restrict__ wc2) {
    int idx = blockIdx.x * 256 + threadIdx.x;       // 0 .. 2*128*1152-1
    int l   = idx / (DD * KCAT);
    int rem = idx % (DD * KCAT);
    int e   = rem / KCAT;
    int md  = rem % KCAT;
    int m = md / DD, d = md % DD;
    const float* W = (l == 0) ? W1 : W2;
    const float* rt = (l == 0) ? r1 : r2;
    float v = (m < 8) ? W[(size_t)m * DD * DD + (size_t)d * DD + e]
                      : rt[(size_t)d * DD + e];
    ((l == 0) ? wc1 : wc2)[rem] = f2bf(v);
}

// per-(dst, r) degree
__global__ __launch_bounds__(256) void hist8_k(const int* __restrict__ dst,
                                               const int* __restrict__ et,
                                               unsigned int* __restrict__ deg8) {
    int e = blockIdx.x * 256 + threadIdx.x;
    if (e >= NE) return;
    atomicAdd(&deg8[(size_t)dst[e] * 8 + et[e]], 1u);
}

// Per node: padded segment base (unordered alloc), per-r sub-bases, dummy pads.
__global__ __launch_bounds__(256) void offs8_k(const unsigned int* __restrict__ deg8,
                                               unsigned int* __restrict__ counter,
                                               unsigned int* __restrict__ pos8,
                                               unsigned int* __restrict__ segBeg,
                                               unsigned int* __restrict__ segLen,
                                               unsigned int* __restrict__ sorted) {
    int node = blockIdx.x * 256 + threadIdx.x;
    if (node >= NN) return;
    const uint4* dp = reinterpret_cast<const uint4*>(&deg8[(size_t)node * 8]);
    uint4 a = dp[0], b = dp[1];
    unsigned int tot = a.x + a.y + a.z + a.w + b.x + b.y + b.z + b.w;
    unsigned int padTot = (tot + 7u) & ~7u;
    unsigned int base = atomicAdd(counter, padTot);
    unsigned int* pp = &pos8[(size_t)node * 8];
    unsigned int run = base;
    pp[0] = run; run += a.x;  pp[1] = run; run += a.y;
    pp[2] = run; run += a.z;  pp[3] = run; run += a.w;
    pp[4] = run; run += b.x;  pp[5] = run; run += b.y;
    pp[6] = run; run += b.z;  pp[7] = run; run += b.w;
    segBeg[node] = base;
    segLen[node] = padTot;
    for (unsigned int p = base + tot; p < base + padTot; ++p)
        sorted[p] = 0xF00000u;                      // dummy: src=0, r=15, deg=0
}

// scatter src | r<<20 | deg<<24 into per-(dst,r) slots (bumps pos8)
__global__ __launch_bounds__(256) void fill8_k(const int* __restrict__ src,
                                               const int* __restrict__ dst,
                                               const int* __restrict__ et,
                                               const unsigned int* __restrict__ deg8,
                                               unsigned int* __restrict__ pos8,
                                               unsigned int* __restrict__ sorted) {
    int e = blockIdx.x * 256 + threadIdx.x;
    if (e >= NE) return;
    int d = dst[e], r = et[e];
    unsigned int p = atomicAdd(&pos8[(size_t)d * 8 + r], 1u);
    unsigned int dg = deg8[(size_t)d * 8 + r];
    if (dg > 255u) dg = 255u;
    sorted[p] = (unsigned int)src[e] | ((unsigned int)r << 20) | (dg << 24);
}

// ---- fused-kernel phase-1 helper macros (static indices only) ----
#define LOAD_BATCH(SEGP, J, RA, RB, HV)                                        \
    do {                                                                       \
        RA = *reinterpret_cast<const uint4*>((SEGP) + (J));                    \
        RB = *reinterpret_cast<const uint4*>((SEGP) + (J) + 4);                \
        HV[0] = *reinterpret_cast<const unsigned int*>(xb + (size_t)(RA.x & 0x1FFFFu) * DD + lane * 2); \
        HV[1] = *reinterpret_cast<const unsigned int*>(xb + (size_t)(RA.y & 0x1FFFFu) * DD + lane * 2); \
        HV[2] = *reinterpret_cast<const unsigned int*>(xb + (size_t)(RA.z & 0x1FFFFu) * DD + lane * 2); \
        HV[3] = *reinterpret_cast<const unsigned int*>(xb + (size_t)(RA.w & 0x1FFFFu) * DD + lane * 2); \
        HV[4] = *reinterpret_cast<const unsigned int*>(xb + (size_t)(RB.x & 0x1FFFFu) * DD + lane * 2); \
        HV[5] = *reinterpret_cast<const unsigned int*>(xb + (size_t)(RB.y & 0x1FFFFu) * DD + lane * 2); \
        HV[6] = *reinterpret_cast<const unsigned int*>(xb + (size_t)(RB.z & 0x1FFFFu) * DD + lane * 2); \
        HV[7] = *reinterpret_cast<const unsigned int*>(xb + (size_t)(RB.w & 0x1FFFFu) * DD + lane * 2); \
    } while (0)

#define PROC_ONE(PKV, HVV, AX, AY, RC, SC, SB, XV)                             \
    do {                                                                       \
        unsigned int r_ = ((PKV) >> 20) & 0xFu;                                \
        if (r_ != (RC)) {                                                      \
            if ((RC) < 8u) {                                                   \
                unsigned int w_ = ((unsigned int)f2bf((AY) * (SC)) << 16)      \
                                | (unsigned int)f2bf((AX) * (SC));             \
                lds32[(SB) + ((((int)(RC) * 16 + lq) ^ (XV)) << 2) + lm] = w_; \
            }                                                                  \
            RC = r_; SC = __builtin_amdgcn_rcpf((float)((PKV) >> 24));         \
            AX = 0.f; AY = 0.f;                                                \
        }                                                                      \
        union { unsigned int u; float f; } lo_, hi_;                           \
        lo_.u = (HVV) << 16; hi_.u = (HVV) & 0xffff0000u;                      \
        AX += lo_.f; AY += hi_.f;                                              \
    } while (0)

#define PROC_BATCH(RA, RB, HV, AX, AY, RC, SC, SB, XV)                         \
    do {                                                                       \
        PROC_ONE(RA.x, HV[0], AX, AY, RC, SC, SB, XV);                         \
        PROC_ONE(RA.y, HV[1], AX, AY, RC, SC, SB, XV);                         \
        PROC_ONE(RA.z, HV[2], AX, AY, RC, SC, SB, XV);                         \
        PROC_ONE(RA.w, HV[3], AX, AY, RC, SC, SB, XV);                         \
        PROC_ONE(RB.x, HV[4], AX, AY, RC, SC, SB, XV);                         \
        PROC_ONE(RB.y, HV[5], AX, AY, RC, SC, SB, XV);                         \
        PROC_ONE(RB.z, HV[6], AX, AY, RC, SC, SB, XV);                         \
        PROC_ONE(RB.w, HV[7], AX, AY, RC, SC, SB, XV);                         \
    } while (0)

#define FLUSH_RUN(AX, AY, RC, SC, SB, XV)                                      \
    do {                                                                       \
        if ((RC) < 8u) {                                                       \
            unsigned int w_ = ((unsigned int)f2bf((AY) * (SC)) << 16)          \
                            | (unsigned int)f2bf((AX) * (SC));                 \
            lds32[(SB) + ((((int)(RC) * 16 + lq) ^ (XV)) << 2) + lm] = w_;     \
        }                                                                      \
    } while (0)

// Fused RGCN layer. Block = 512 thr = 8 waves = 16 dst nodes (2/wave, dual-stream).
// Phase 1: wave walks its 2 nodes' r-sorted padded segments as interleaved
//          8-deep load pipelines; run-flush per relation into swizzled LDS.
// Phase 2: wave w computes out[16 nodes][cols 16w..16w+15] = xagg @ Wcat^T.
// mode 1: bf16 store (next layer input); mode 2: f32 store (final output).
__global__ __launch_bounds__(512, 8) void fused_k(const unsigned short* __restrict__ xb,
                                                  const unsigned short* __restrict__ wcat,
                                                  const float* __restrict__ bias,
                                                  const unsigned int* __restrict__ sorted,
                                                  const unsigned int* __restrict__ segBeg,
                                                  const unsigned int* __restrict__ segLen,
                                                  unsigned short* __restrict__ obf,
                                                  float* __restrict__ of32,
                                                  int mode) {
    __shared__ unsigned short ldsx[16 * KCAT];      // 36,864 B
    const int wave = threadIdx.x >> 6;              // 0..7
    const int lane = threadIdx.x & 63;
    const int c16  = lane & 15;
    const int grp  = lane >> 4;
    const int lq   = lane >> 2;
    const int lm   = lane & 3;
    const int blk  = blockIdx.x;
    unsigned int* lds32 = reinterpret_cast<unsigned int*>(ldsx);

    // ---------- phase 1: dual-stream gather + run-flush ----------
    const int row0 = wave * 2, row1 = wave * 2 + 1;
    const int node0 = blk * 16 + row0, node1 = blk * 16 + row1;
    const int sb0 = row0 * (KCAT / 2), sb1 = row1 * (KCAT / 2);
    const int xv0 = row0 & 7, xv1 = row1 & 7;

    // pre-zero relation slices, write root slice (m=8) for both rows
#pragma unroll
    for (int r = 0; r < 8; ++r) {
        lds32[sb0 + (((r * 16 + lq) ^ xv0) << 2) + lm] = 0u;
        lds32[sb1 + (((r * 16 + lq) ^ xv1) << 2) + lm] = 0u;
    }
    lds32[sb0 + (((128 + lq) ^ xv0) << 2) + lm] =
        *reinterpret_cast<const unsigned int*>(xb + (size_t)node0 * DD + lane * 2);
    lds32[sb1 + (((128 + lq) ^ xv1) << 2) + lm] =
        *reinterpret_cast<const unsigned int*>(xb + (size_t)node1 * DD + lane * 2);

    const unsigned int* segp0 = sorted +
        (unsigned int)__builtin_amdgcn_readfirstlane((int)segBeg[node0]);
    const unsigned int* segp1 = sorted +
        (unsigned int)__builtin_amdgcn_readfirstlane((int)segBeg[node1]);
    const unsigned int len0 =
        (unsigned int)__builtin_amdgcn_readfirstlane((int)segLen[node0]);
    const unsigned int len1 =
        (unsigned int)__builtin_amdgcn_readfirstlane((int)segLen[node1]);

    unsigned int j0 = 0, j1 = 0;
    float ax0 = 0.f, ay0 = 0.f, ax1 = 0.f, ay1 = 0.f, sc0 = 0.f, sc1 = 0.f;
    unsigned int rc0 = 15u, rc1 = 15u;
    uint4 ra0, rb0, ra1, rb1;
    unsigned int hv0[8], hv1[8];

    bool v0 = (j0 < len0), v1 = (j1 < len1);
    if (v0) LOAD_BATCH(segp0, j0, ra0, rb0, hv0);
    if (v1) LOAD_BATCH(segp1, j1, ra1, rb1, hv1);
    while (v0 || v1) {
        if (v0) {
            PROC_BATCH(ra0, rb0, hv0, ax0, ay0, rc0, sc0, sb0, xv0);
            j0 += 8; v0 = (j0 < len0);
            if (v0) LOAD_BATCH(segp0, j0, ra0, rb0, hv0);
        }
        if (v1) {
            PROC_BATCH(ra1, rb1, hv1, ax1, ay1, rc1, sc1, sb1, xv1);
            j1 += 8; v1 = (j1 < len1);
            if (v1) LOAD_BATCH(segp1, j1, ra1, rb1, hv1);
        }
    }
    FLUSH_RUN(ax0, ay0, rc0, sc0, sb0, xv0);
    FLUSH_RUN(ax1, ay1, rc1, sc1, sb1, xv1);
    __syncthreads();

    // ---------- phase 2: MFMA out = xagg @ Wcat^T (wave w -> col tile w) ----------
    f32x4 acc = f32x4{0.f, 0.f, 0.f, 0.f};
    const unsigned short* arow = wcat + (size_t)(wave * 16 + c16) * KCAT;
#pragma unroll
    for (int kk = 0; kk < KCAT / 32; ++kk) {        // 36 k-steps
        int slot = (kk * 4 + grp) ^ (c16 & 7);
        bf16x8 b = *reinterpret_cast<const bf16x8*>(&ldsx[c16 * KCAT + slot * 8]);
        bf16x8 a = *reinterpret_cast<const bf16x8*>(arow + kk * 32 + grp * 8);
        acc = __builtin_amdgcn_mfma_f32_16x16x32_bf16(a, b, acc, 0, 0, 0);
    }

    // ---------- epilogue: +bias, relu, store ----------
    const int node = blk * 16 + c16;
    const int od = wave * 16 + grp * 4;
    const float4 bv = *reinterpret_cast<const float4*>(bias + od);
    float o0 = fmaxf(acc[0] + bv.x, 0.f);
    float o1 = fmaxf(acc[1] + bv.y, 0.f);
    float o2 = fmaxf(acc[2] + bv.z, 0.f);
    float o3 = fmaxf(acc[3] + bv.w, 0.f);
    if (mode == 1) {
        union { unsigned short s[4]; uint2 v; } pko;
        pko.s[0] = f2bf(o0); pko.s[1] = f2bf(o1);
        pko.s[2] = f2bf(o2); pko.s[3] = f2bf(o3);
        *reinterpret_cast<uint2*>(obf + (size_t)node * DD + od) = pko.v;
    } else {
        *reinterpret_cast<float4*>(of32 + (size_t)node * DD + od)
            = make_float4(o0, o1, o2, o3);
    }
}

extern "C" void kernel_launch(void* const* d_in, const int* in_sizes, int n_in,
                              void* d_out, int out_size, void* d_ws, size_t ws_size,
                              hipStream_t stream) {
    const float* x  = (const float*)d_in[0];
    const int*   ei = (const int*)d_in[1];
    const int*   et = (const int*)d_in[2];
    const float* W1 = (const float*)d_in[3];
    const float* r1 = (const float*)d_in[4];
    const float* b1 = (const float*)d_in[5];
    const float* W2 = (const float*)d_in[6];
    const float* r2 = (const float*)d_in[7];
    const float* b2 = (const float*)d_in[8];
    float* out = (float*)d_out;

    // workspace (~66 MB)
    char* ws = (char*)d_ws;
    unsigned int*   deg8    = (unsigned int*)ws;                 // NN*8 u32 = 3.2 MB
    unsigned int*   counter = deg8 + (size_t)NN * 8;             // 1 u32 (pad 64)
    unsigned int*   pos8    = counter + 64;                      // NN*8 u32 = 3.2 MB
    unsigned int*   segBeg  = pos8 + (size_t)NN * 8;             // NN u32
    unsigned int*   segLen  = segBeg + NN;                       // NN u32
    unsigned int*   sorted  = segLen + NN;                       // (NE+7*NN) u32 = 6.8 MB
    unsigned short* wc1     = (unsigned short*)(sorted + NE + 7 * NN);  // 294,912 B
    unsigned short* wc2     = wc1 + DD * KCAT;
    unsigned short* xbuf    = wc2 + DD * KCAT;                   // 25.6 MB
    unsigned short* xbuf2   = xbuf + (size_t)NN * DD;            // 25.6 MB
    size_t need = (size_t)((char*)(xbuf2 + (size_t)NN * DD) - ws);
    if (ws_size < need) return;                                  // loud failure

    const int* srcv = ei;
    const int* dstv = ei + NE;

    hipMemsetAsync(deg8, 0, ((size_t)NN * 8 + 64) * 4, stream);  // deg8 + counter
    cvt_x_k<<<(NN * DD / 4) / 256, 256, 0, stream>>>(x, xbuf, NN * DD / 4);
    cvt_w_k<<<(2 * DD * KCAT) / 256, 256, 0, stream>>>(W1, r1, W2, r2, wc1, wc2);
    hist8_k<<<(NE + 255) / 256, 256, 0, stream>>>(dstv, et, deg8);
    offs8_k<<<(NN + 255) / 256, 256, 0, stream>>>(deg8, counter, pos8, segBeg, segLen, sorted);
    fill8_k<<<(NE + 255) / 256, 256, 0, stream>>>(srcv, dstv, et, deg8, pos8, sorted);

    fused_k<<<NBLK, 512, 0, stream>>>(xbuf,  wc1, b1, sorted, segBeg, segLen,
                                      xbuf2, (float*)nullptr, 1);
    fused_k<<<NBLK, 512, 0, stream>>>(xbuf2, wc2, b2, sorted, segBeg, segLen,
                                      (unsigned short*)nullptr, out, 2);
}